// Round 5
// baseline (792.352 us; speedup 1.0000x reference)
//
#include <hip/hip_runtime.h>

#define C_DIM 256
#define P_DIM 2048
#define L_DIM 1024
#define N_DIM 16
#define KEEP 102
#define KPAD 108   // KEEP rounded up for branch-free 4-wide prefetch

// ---------------- kernel 1a: pinv[p] = 1/||pool_p|| ----------------
__global__ __launch_bounds__(256) void k_pinv(const float* __restrict__ pool,
                                              float* __restrict__ pinv) {
  int p = blockIdx.x * 256 + threadIdx.x;
  const float4* row = (const float4*)(pool + (size_t)p * C_DIM);
  float s = 0.f;
#pragma unroll
  for (int i = 0; i < C_DIM / 4; ++i) {
    float4 v = row[i];
    s += v.x * v.x + v.y * v.y + v.z * v.z + v.w * v.w;
  }
  pinv[p] = 1.0f / sqrtf(s);
}

// ------------- kernel 1b: poolTs[c][p] = pool[p][c] * pinv[p] -------------
__global__ __launch_bounds__(256) void k_transpose(const float* __restrict__ pool,
                                                   const float* __restrict__ pinv,
                                                   float* __restrict__ poolTs) {
  __shared__ float tile[32][33];
  __shared__ float pv[32];
  int bx = blockIdx.x & 63;
  int by = blockIdx.x >> 6;
  int tx = threadIdx.x & 31, ty = threadIdx.x >> 5;
  int p0 = bx * 32, c0 = by * 32;
  if (threadIdx.x < 32) pv[threadIdx.x] = pinv[p0 + threadIdx.x];
#pragma unroll
  for (int k = 0; k < 4; ++k)
    tile[ty + 8 * k][tx] = pool[(size_t)(p0 + ty + 8 * k) * C_DIM + c0 + tx];
  __syncthreads();
#pragma unroll
  for (int k = 0; k < 4; ++k)
    poolTs[(size_t)(c0 + ty + 8 * k) * P_DIM + p0 + tx] = tile[tx][ty + 8 * k] * pv[tx];
}

// ---------------- kernel A: sbuf[pix][p] = sum_c poolTs[c][p] * x[n][c][l] ----
// 128x128 tile, K-step 16, 256 threads, 8x8 acc, 4+4 microtile split,
// double-buffered LDS with a SINGLE barrier per K-tile (loads for tile k+1
// issued before computing tile k; vmcnt drain hidden under ~2048 FMA cycles).
__global__ __launch_bounds__(256) void k_gemm(const float* __restrict__ poolTs,
                                              const float* __restrict__ x,
                                              float* __restrict__ sbuf) {
  __shared__ float As[2][16][128];
  __shared__ float Bs[2][16][128];
  const int t = threadIdx.x;
  const int tx = t & 15, ty = t >> 4;
  const int pT = blockIdx.x & 15;       // p tile (16)
  const int pixT = blockIdx.x >> 4;     // pixel tile (128)
  const int p0 = pT * 128;
  const int n = pixT >> 3;
  const int l0 = (pixT & 7) * 128;
  const int pix0 = pixT * 128;

  const int r = t >> 5;           // 0..7
  const int c4 = (t & 31) * 4;    // 0..124

  const float* gA0 = poolTs + (size_t)r * P_DIM + p0 + c4;
  const float* gB0 = x + ((size_t)(n * C_DIM + r)) * L_DIM + l0 + c4;

  float acc[8][8];                // [p-sub][pix-sub]
#pragma unroll
  for (int j = 0; j < 8; ++j)
#pragma unroll
    for (int i = 0; i < 8; ++i) acc[j][i] = 0.f;

  // prologue: stage tile 0 into buf 0
  {
    float4 a0v = *(const float4*)gA0;
    float4 a1v = *(const float4*)(gA0 + 8 * P_DIM);
    float4 b0v = *(const float4*)gB0;
    float4 b1v = *(const float4*)(gB0 + 8 * L_DIM);
    *(float4*)&As[0][r][c4] = a0v;
    *(float4*)&As[0][r + 8][c4] = a1v;
    *(float4*)&Bs[0][r][c4] = b0v;
    *(float4*)&Bs[0][r + 8][c4] = b1v;
  }
  __syncthreads();

#pragma unroll 2
  for (int kt = 0; kt < 16; ++kt) {
    const int cur = kt & 1;
    float4 a0v, a1v, b0v, b1v;
    if (kt < 15) {                 // issue next tile's loads (async, no use yet)
      const float* gA = gA0 + (size_t)(kt + 1) * 16 * P_DIM;
      const float* gB = gB0 + (size_t)(kt + 1) * 16 * L_DIM;
      a0v = *(const float4*)gA;
      a1v = *(const float4*)(gA + 8 * P_DIM);
      b0v = *(const float4*)gB;
      b1v = *(const float4*)(gB + 8 * L_DIM);
    }
#pragma unroll
    for (int kk = 0; kk < 16; ++kk) {
      float4 fa0 = *(const float4*)&As[cur][kk][tx * 4];
      float4 fa1 = *(const float4*)&As[cur][kk][64 + tx * 4];
      float4 fb0 = *(const float4*)&Bs[cur][kk][ty * 4];
      float4 fb1 = *(const float4*)&Bs[cur][kk][64 + ty * 4];
      float ar[8] = {fa0.x, fa0.y, fa0.z, fa0.w, fa1.x, fa1.y, fa1.z, fa1.w};
      float br[8] = {fb0.x, fb0.y, fb0.z, fb0.w, fb1.x, fb1.y, fb1.z, fb1.w};
#pragma unroll
      for (int j = 0; j < 8; ++j)
#pragma unroll
        for (int i = 0; i < 8; ++i) acc[j][i] = fmaf(ar[j], br[i], acc[j][i]);
    }
    if (kt < 15) {                 // write tile k+1 (vmcnt drained here), 1 barrier
      const int nxt = cur ^ 1;
      *(float4*)&As[nxt][r][c4] = a0v;
      *(float4*)&As[nxt][r + 8][c4] = a1v;
      *(float4*)&Bs[nxt][r][c4] = b0v;
      *(float4*)&Bs[nxt][r + 8][c4] = b1v;
      __syncthreads();
    }
  }

  // stores: pix rows ty*4+i and 64+ty*4+i; p cols tx*4 and 64+tx*4
#pragma unroll
  for (int i = 0; i < 4; ++i) {
    float* dst0 = sbuf + (size_t)(pix0 + ty * 4 + i) * P_DIM + p0;
    *(float4*)(dst0 + tx * 4) = make_float4(acc[0][i], acc[1][i], acc[2][i], acc[3][i]);
    *(float4*)(dst0 + 64 + tx * 4) = make_float4(acc[4][i], acc[5][i], acc[6][i], acc[7][i]);
    float* dst1 = sbuf + (size_t)(pix0 + 64 + ty * 4 + i) * P_DIM + p0;
    *(float4*)(dst1 + tx * 4) = make_float4(acc[0][4 + i], acc[1][4 + i], acc[2][4 + i], acc[3][4 + i]);
    *(float4*)(dst1 + 64 + tx * 4) = make_float4(acc[4][4 + i], acc[5][4 + i], acc[6][4 + i], acc[7][4 + i]);
  }
}

// ---------------- kernel B: per-pixel top-102 select + renorm + recon ----
// 512 threads = 8 waves; wave wv owns pixel l0+wv. 2048 blocks.
// value (q, rr) at lane: p = q*256 + lane*4 + rr  (float4 loads, 1 KB/instr)
__global__ __launch_bounds__(512) void k_select(const float* __restrict__ sbuf,
                                                const float* __restrict__ pool,
                                                float* __restrict__ out) {
  __shared__ __align__(16) float tbuf[8][260];  // [pix][c] transpose buffer
  __shared__ int2 kpw[8][KPAD];                 // kept (p, bits(s)) per pixel

  const int t = threadIdx.x;
  const int lane = t & 63;
  const int wv = t >> 6;               // local pixel 0..7
  const int b = blockIdx.x;
  const int n = b >> 7;
  const int l0 = (b & 127) * 8;
  const float* sp = sbuf + (size_t)(n * L_DIM + l0 + wv) * P_DIM;

  float4 v[8];
#pragma unroll
  for (int q = 0; q < 8; ++q) v[q] = *(const float4*)(sp + q * 256 + lane * 4);

  // zero-init prefetch pad of the kept list (lanes 0..KPAD-KEEP-1)
  if (lane < KPAD - KEEP) kpw[wv][KEEP + lane] = make_int2(0, 0);

  // ---- exact binary search on positive-float bit pattern (31 rounds),
  //      wave-uniform count via ballot+popc ----
  unsigned lo = 0u, hi = 0x7F800000u;
  for (int it = 0; it < 31; ++it) {
    unsigned m = lo + ((hi - lo) >> 1);
    float mf = __uint_as_float(m);
    unsigned cnt = 0;
#pragma unroll
    for (int q = 0; q < 8; ++q) {
      cnt += (unsigned)__popcll(__ballot(fabsf(v[q].x) >= mf));
      cnt += (unsigned)__popcll(__ballot(fabsf(v[q].y) >= mf));
      cnt += (unsigned)__popcll(__ballot(fabsf(v[q].z) >= mf));
      cnt += (unsigned)__popcll(__ballot(fabsf(v[q].w) >= mf));
    }
    if (cnt >= KEEP) lo = m; else hi = m;
  }
  const float V = __uint_as_float(lo);
  const float Vp = __uint_as_float(lo + 1u);   // strictly-greater threshold

  unsigned gt = 0;
#pragma unroll
  for (int q = 0; q < 8; ++q) {
    gt += (unsigned)__popcll(__ballot(fabsf(v[q].x) >= Vp));
    gt += (unsigned)__popcll(__ballot(fabsf(v[q].y) >= Vp));
    gt += (unsigned)__popcll(__ballot(fabsf(v[q].z) >= Vp));
    gt += (unsigned)__popcll(__ballot(fabsf(v[q].w) >= Vp));
  }
  const unsigned rrem = (unsigned)KEEP - gt;   // ties kept (smallest p first)

  // ---- masks: strictly-greater / equal-to-V (4 bits each, rr-indexed) ----
  unsigned gmask[8], tmask[8];
#pragma unroll
  for (int q = 0; q < 8; ++q) {
    const float* f = (const float*)&v[q];
    unsigned gm = 0, tm = 0;
#pragma unroll
    for (int rr = 0; rr < 4; ++rr) {
      float av = fabsf(f[rr]);
      if (av >= Vp) gm |= (1u << rr);
      else if (av >= V) tm |= (1u << rr);
    }
    gmask[q] = gm; tmask[q] = tm;
  }

  // ---- single pass: exact tie-break (ascending p) + compaction + Ssum ----
  const unsigned long long lowm = (1ull << lane) - 1ull;
  unsigned base = 0, tiebase = 0;
  float Ssum = 0.f;
#pragma unroll
  for (int q = 0; q < 8; ++q) {
    const float* f = (const float*)&v[q];
    // tie ranking within q-group (p-order = (lane, rr) lex order)
    unsigned teq = 0, myeqb = 0;
#pragma unroll
    for (int rr = 0; rr < 4; ++rr) {
      unsigned long long beq = __ballot((tmask[q] >> rr) & 1u);
      teq += (unsigned)__popcll(beq);
      myeqb += (unsigned)__popcll(beq & lowm);
    }
    unsigned km = gmask[q];
    {
      unsigned cum = 0;
#pragma unroll
      for (int rr = 0; rr < 4; ++rr) {
        if ((tmask[q] >> rr) & 1u) {
          if (tiebase + myeqb + cum < rrem) km |= (1u << rr);
          ++cum;
        }
      }
    }
    // compaction of kept in ascending-p order
    unsigned long long bk[4];
    unsigned tot = 0, myb = 0;
#pragma unroll
    for (int rr = 0; rr < 4; ++rr) {
      bk[rr] = __ballot((km >> rr) & 1u);
      tot += (unsigned)__popcll(bk[rr]);
      myb += (unsigned)__popcll(bk[rr] & lowm);
    }
    {
      unsigned cum = 0;
#pragma unroll
      for (int rr = 0; rr < 4; ++rr) {
        if ((km >> rr) & 1u) {
          unsigned pos = base + myb + cum;
          kpw[wv][pos] = make_int2(q * 256 + lane * 4 + rr, __float_as_int(f[rr]));
          Ssum += f[rr];
          ++cum;
        }
      }
    }
    base += tot;
    tiebase += teq;
  }

  // ---- invS (applied at final scale) ----
#pragma unroll
  for (int off = 1; off < 64; off <<= 1) Ssum += __shfl_xor(Ssum, off);
  const float invS = 1.0f / Ssum;

  __builtin_amdgcn_wave_barrier();   // wave-local LDS produce->consume

  // ---- reconstruct: out_c = invS * sum_kept s_p * pool[p][c], c=4*lane+j
  //      4-wide groups, 4-deep load prefetch, zero-weight pad (branch-free) ----
  float a0 = 0.f, a1 = 0.f, a2 = 0.f, a3 = 0.f;
  const float* pb = pool + 4 * lane;
  int2 e[4];
  float4 r[4];
#pragma unroll
  for (int j = 0; j < 4; ++j) e[j] = kpw[wv][j];
#pragma unroll
  for (int j = 0; j < 4; ++j) r[j] = *(const float4*)(pb + (size_t)e[j].x * C_DIM);
  for (int k = 0; k < 104; k += 4) {
    int kn = (k + 4 < 104) ? k + 4 : 0;     // dummy prefetch on last group
    int2 en[4];
    float4 rn[4];
#pragma unroll
    for (int j = 0; j < 4; ++j) en[j] = kpw[wv][kn + j];
#pragma unroll
    for (int j = 0; j < 4; ++j) rn[j] = *(const float4*)(pb + (size_t)en[j].x * C_DIM);
#pragma unroll
    for (int j = 0; j < 4; ++j) {
      float w = __int_as_float(e[j].y);
      a0 = fmaf(w, r[j].x, a0); a1 = fmaf(w, r[j].y, a1);
      a2 = fmaf(w, r[j].z, a2); a3 = fmaf(w, r[j].w, a3);
    }
#pragma unroll
    for (int j = 0; j < 4; ++j) { e[j] = en[j]; r[j] = rn[j]; }
  }
  a0 *= invS; a1 *= invS; a2 *= invS; a3 *= invS;

  *(float4*)&tbuf[wv][4 * lane] = make_float4(a0, a1, a2, a3);
  __syncthreads();

  // coalesced store: thread t -> c = t>>1, pixel quad = (t&1)*4
  {
    int c = t >> 1, lq = t & 1;
    float4 o = make_float4(tbuf[4 * lq + 0][c], tbuf[4 * lq + 1][c],
                           tbuf[4 * lq + 2][c], tbuf[4 * lq + 3][c]);
    *(float4*)(out + ((size_t)(n * C_DIM + c)) * L_DIM + l0 + 4 * lq) = o;
  }
}

// ---------------- launch ----------------
extern "C" void kernel_launch(void* const* d_in, const int* in_sizes, int n_in,
                              void* d_out, int out_size, void* d_ws, size_t ws_size,
                              hipStream_t stream) {
  const float* x = (const float*)d_in[0];
  const float* pool = (const float*)d_in[1];
  float* out = (float*)d_out;
  float* poolTs = (float*)d_ws;                          // 2 MB
  float* pinv = poolTs + (size_t)C_DIM * P_DIM;          // + 8 KB
  float* sbuf = pinv + P_DIM;                            // 134.2 MB scores
  k_pinv<<<P_DIM / 256, 256, 0, stream>>>(pool, pinv);
  k_transpose<<<(P_DIM / 32) * (C_DIM / 32), 256, 0, stream>>>(pool, pinv, poolTs);
  k_gemm<<<16 * 128, 256, 0, stream>>>(poolTs, x, sbuf);
  k_select<<<2048, 512, 0, stream>>>(sbuf, pool, out);
}

// Round 6
// 376.646 us; speedup vs baseline: 2.1037x; 2.1037x over previous
//
#include <hip/hip_runtime.h>

#define C_DIM 256
#define P_DIM 2048
#define L_DIM 1024
#define N_DIM 16
#define KEEP 102
#define KPAD 108   // KEEP rounded up for branch-free 4-wide prefetch

// async global->LDS 16B direct copy (no VGPR round-trip)
#define GLD_LDS16(gp, lp)                                                    \
  __builtin_amdgcn_global_load_lds(                                          \
      (const __attribute__((address_space(1))) void*)(gp),                   \
      (__attribute__((address_space(3))) void*)(lp), 16, 0, 0)

// ---------------- kernel 1a: pinv[p] = 1/||pool_p|| ----------------
__global__ __launch_bounds__(256) void k_pinv(const float* __restrict__ pool,
                                              float* __restrict__ pinv) {
  int p = blockIdx.x * 256 + threadIdx.x;
  const float4* row = (const float4*)(pool + (size_t)p * C_DIM);
  float s = 0.f;
#pragma unroll
  for (int i = 0; i < C_DIM / 4; ++i) {
    float4 v = row[i];
    s += v.x * v.x + v.y * v.y + v.z * v.z + v.w * v.w;
  }
  pinv[p] = 1.0f / sqrtf(s);
}

// ------------- kernel 1b: poolTs[c][p] = pool[p][c] * pinv[p] -------------
__global__ __launch_bounds__(256) void k_transpose(const float* __restrict__ pool,
                                                   const float* __restrict__ pinv,
                                                   float* __restrict__ poolTs) {
  __shared__ float tile[32][33];
  __shared__ float pv[32];
  int bx = blockIdx.x & 63;
  int by = blockIdx.x >> 6;
  int tx = threadIdx.x & 31, ty = threadIdx.x >> 5;
  int p0 = bx * 32, c0 = by * 32;
  if (threadIdx.x < 32) pv[threadIdx.x] = pinv[p0 + threadIdx.x];
#pragma unroll
  for (int k = 0; k < 4; ++k)
    tile[ty + 8 * k][tx] = pool[(size_t)(p0 + ty + 8 * k) * C_DIM + c0 + tx];
  __syncthreads();
#pragma unroll
  for (int k = 0; k < 4; ++k)
    poolTs[(size_t)(c0 + ty + 8 * k) * P_DIM + p0 + tx] = tile[tx][ty + 8 * k] * pv[tx];
}

// ---------------- kernel A: sbuf[pix][p] = sum_c poolTs[c][p] * x[n][c][l] ----
// 128x128 tile, K-step 16, 256 threads, 8x8 acc, 4+4 microtile split,
// double-buffered LDS staged via async global_load_lds (16B), ONE barrier
// per K-tile. Loads for tile k+1 are in flight during tile k's 1024 FMAs,
// so the vmcnt drain at the barrier is hidden. Zero staging VGPRs.
__global__ __launch_bounds__(256) void k_gemm(const float* __restrict__ poolTs,
                                              const float* __restrict__ x,
                                              float* __restrict__ sbuf) {
  __shared__ float As[2][16][128];   // 2 x 8 KB
  __shared__ float Bs[2][16][128];   // 2 x 8 KB
  const int t = threadIdx.x;
  const int tx = t & 15, ty = t >> 4;
  const int pT = blockIdx.x & 15;       // p tile (16)
  const int pixT = blockIdx.x >> 4;     // pixel tile (128)
  const int p0 = pT * 128;
  const int n = pixT >> 3;
  const int l0 = (pixT & 7) * 128;
  const int pix0 = pixT * 128;

  const int r = t >> 5;           // 0..7
  const int c4 = (t & 31) * 4;    // 0..124

  const float* gA0 = poolTs + (size_t)r * P_DIM + p0 + c4;
  const float* gB0 = x + ((size_t)(n * C_DIM + r)) * L_DIM + l0 + c4;

  float acc[8][8];                // [p-sub][pix-sub]
#pragma unroll
  for (int j = 0; j < 8; ++j)
#pragma unroll
    for (int i = 0; i < 8; ++i) acc[j][i] = 0.f;

  // prologue: async-stage tile 0 into buf 0
  GLD_LDS16(gA0, &As[0][r][c4]);
  GLD_LDS16(gA0 + 8 * P_DIM, &As[0][r + 8][c4]);
  GLD_LDS16(gB0, &Bs[0][r][c4]);
  GLD_LDS16(gB0 + 8 * L_DIM, &Bs[0][r + 8][c4]);
  __syncthreads();   // vmcnt(0) drain + barrier (compiler-inserted)

#pragma unroll 1
  for (int kt = 0; kt < 16; ++kt) {
    const int cur = kt & 1;
    if (kt < 15) {                 // async loads into the other buffer
      const int nxt = cur ^ 1;
      const float* gA = gA0 + (size_t)(kt + 1) * 16 * P_DIM;
      const float* gB = gB0 + (size_t)(kt + 1) * 16 * L_DIM;
      GLD_LDS16(gA, &As[nxt][r][c4]);
      GLD_LDS16(gA + 8 * P_DIM, &As[nxt][r + 8][c4]);
      GLD_LDS16(gB, &Bs[nxt][r][c4]);
      GLD_LDS16(gB + 8 * L_DIM, &Bs[nxt][r + 8][c4]);
    }
#pragma unroll
    for (int kk = 0; kk < 16; ++kk) {
      float4 fa0 = *(const float4*)&As[cur][kk][tx * 4];
      float4 fa1 = *(const float4*)&As[cur][kk][64 + tx * 4];
      float4 fb0 = *(const float4*)&Bs[cur][kk][ty * 4];
      float4 fb1 = *(const float4*)&Bs[cur][kk][64 + ty * 4];
      float ar[8] = {fa0.x, fa0.y, fa0.z, fa0.w, fa1.x, fa1.y, fa1.z, fa1.w};
      float br[8] = {fb0.x, fb0.y, fb0.z, fb0.w, fb1.x, fb1.y, fb1.z, fb1.w};
#pragma unroll
      for (int j = 0; j < 8; ++j)
#pragma unroll
        for (int i = 0; i < 8; ++i) acc[j][i] = fmaf(ar[j], br[i], acc[j][i]);
    }
    __syncthreads();   // drains vmcnt (in-flight next-tile loads) + lgkm
  }

  // stores: pix rows ty*4+i and 64+ty*4+i; p cols tx*4 and 64+tx*4
#pragma unroll
  for (int i = 0; i < 4; ++i) {
    float* dst0 = sbuf + (size_t)(pix0 + ty * 4 + i) * P_DIM + p0;
    *(float4*)(dst0 + tx * 4) = make_float4(acc[0][i], acc[1][i], acc[2][i], acc[3][i]);
    *(float4*)(dst0 + 64 + tx * 4) = make_float4(acc[4][i], acc[5][i], acc[6][i], acc[7][i]);
    float* dst1 = sbuf + (size_t)(pix0 + 64 + ty * 4 + i) * P_DIM + p0;
    *(float4*)(dst1 + tx * 4) = make_float4(acc[0][4 + i], acc[1][4 + i], acc[2][4 + i], acc[3][4 + i]);
    *(float4*)(dst1 + 64 + tx * 4) = make_float4(acc[4][4 + i], acc[5][4 + i], acc[6][4 + i], acc[7][4 + i]);
  }
}

// ---------------- kernel B: per-pixel top-102 select + renorm + recon ----
// 512 threads = 8 waves; wave wv owns pixel l0+wv. 2048 blocks.
// value (q, rr) at lane: p = q*256 + lane*4 + rr  (float4 loads, 1 KB/instr)
__global__ __launch_bounds__(512) void k_select(const float* __restrict__ sbuf,
                                                const float* __restrict__ pool,
                                                float* __restrict__ out) {
  __shared__ __align__(16) float tbuf[8][260];  // [pix][c] transpose buffer
  __shared__ int2 kpw[8][KPAD];                 // kept (p, bits(s)) per pixel

  const int t = threadIdx.x;
  const int lane = t & 63;
  const int wv = t >> 6;               // local pixel 0..7
  const int b = blockIdx.x;
  const int n = b >> 7;
  const int l0 = (b & 127) * 8;
  const float* sp = sbuf + (size_t)(n * L_DIM + l0 + wv) * P_DIM;

  float4 v[8];
#pragma unroll
  for (int q = 0; q < 8; ++q) v[q] = *(const float4*)(sp + q * 256 + lane * 4);

  // zero-init prefetch pad of the kept list (lanes 0..KPAD-KEEP-1)
  if (lane < KPAD - KEEP) kpw[wv][KEEP + lane] = make_int2(0, 0);

  // ---- exact binary search on positive-float bit pattern (31 rounds),
  //      wave-uniform count via ballot+popc ----
  unsigned lo = 0u, hi = 0x7F800000u;
  for (int it = 0; it < 31; ++it) {
    unsigned m = lo + ((hi - lo) >> 1);
    float mf = __uint_as_float(m);
    unsigned cnt = 0;
#pragma unroll
    for (int q = 0; q < 8; ++q) {
      cnt += (unsigned)__popcll(__ballot(fabsf(v[q].x) >= mf));
      cnt += (unsigned)__popcll(__ballot(fabsf(v[q].y) >= mf));
      cnt += (unsigned)__popcll(__ballot(fabsf(v[q].z) >= mf));
      cnt += (unsigned)__popcll(__ballot(fabsf(v[q].w) >= mf));
    }
    if (cnt >= KEEP) lo = m; else hi = m;
  }
  const float V = __uint_as_float(lo);
  const float Vp = __uint_as_float(lo + 1u);   // strictly-greater threshold

  unsigned gt = 0;
#pragma unroll
  for (int q = 0; q < 8; ++q) {
    gt += (unsigned)__popcll(__ballot(fabsf(v[q].x) >= Vp));
    gt += (unsigned)__popcll(__ballot(fabsf(v[q].y) >= Vp));
    gt += (unsigned)__popcll(__ballot(fabsf(v[q].z) >= Vp));
    gt += (unsigned)__popcll(__ballot(fabsf(v[q].w) >= Vp));
  }
  const unsigned rrem = (unsigned)KEEP - gt;   // ties kept (smallest p first)

  // ---- masks: strictly-greater / equal-to-V (4 bits each, rr-indexed) ----
  unsigned gmask[8], tmask[8];
#pragma unroll
  for (int q = 0; q < 8; ++q) {
    const float* f = (const float*)&v[q];
    unsigned gm = 0, tm = 0;
#pragma unroll
    for (int rr = 0; rr < 4; ++rr) {
      float av = fabsf(f[rr]);
      if (av >= Vp) gm |= (1u << rr);
      else if (av >= V) tm |= (1u << rr);
    }
    gmask[q] = gm; tmask[q] = tm;
  }

  // ---- single pass: exact tie-break (ascending p) + compaction + Ssum ----
  const unsigned long long lowm = (1ull << lane) - 1ull;
  unsigned base = 0, tiebase = 0;
  float Ssum = 0.f;
#pragma unroll
  for (int q = 0; q < 8; ++q) {
    const float* f = (const float*)&v[q];
    // tie ranking within q-group (p-order = (lane, rr) lex order)
    unsigned teq = 0, myeqb = 0;
#pragma unroll
    for (int rr = 0; rr < 4; ++rr) {
      unsigned long long beq = __ballot((tmask[q] >> rr) & 1u);
      teq += (unsigned)__popcll(beq);
      myeqb += (unsigned)__popcll(beq & lowm);
    }
    unsigned km = gmask[q];
    {
      unsigned cum = 0;
#pragma unroll
      for (int rr = 0; rr < 4; ++rr) {
        if ((tmask[q] >> rr) & 1u) {
          if (tiebase + myeqb + cum < rrem) km |= (1u << rr);
          ++cum;
        }
      }
    }
    // compaction of kept in ascending-p order
    unsigned long long bk[4];
    unsigned tot = 0, myb = 0;
#pragma unroll
    for (int rr = 0; rr < 4; ++rr) {
      bk[rr] = __ballot((km >> rr) & 1u);
      tot += (unsigned)__popcll(bk[rr]);
      myb += (unsigned)__popcll(bk[rr] & lowm);
    }
    {
      unsigned cum = 0;
#pragma unroll
      for (int rr = 0; rr < 4; ++rr) {
        if ((km >> rr) & 1u) {
          unsigned pos = base + myb + cum;
          kpw[wv][pos] = make_int2(q * 256 + lane * 4 + rr, __float_as_int(f[rr]));
          Ssum += f[rr];
          ++cum;
        }
      }
    }
    base += tot;
    tiebase += teq;
  }

  // ---- invS (applied at final scale) ----
#pragma unroll
  for (int off = 1; off < 64; off <<= 1) Ssum += __shfl_xor(Ssum, off);
  const float invS = 1.0f / Ssum;

  __builtin_amdgcn_wave_barrier();   // wave-local LDS produce->consume

  // ---- reconstruct: out_c = invS * sum_kept s_p * pool[p][c], c=4*lane+j
  //      4-wide groups, 4-deep load prefetch, zero-weight pad (branch-free) ----
  float a0 = 0.f, a1 = 0.f, a2 = 0.f, a3 = 0.f;
  const float* pb = pool + 4 * lane;
  int2 e[4];
  float4 r[4];
#pragma unroll
  for (int j = 0; j < 4; ++j) e[j] = kpw[wv][j];
#pragma unroll
  for (int j = 0; j < 4; ++j) r[j] = *(const float4*)(pb + (size_t)e[j].x * C_DIM);
  for (int k = 0; k < 104; k += 4) {
    int kn = (k + 4 < 104) ? k + 4 : 0;     // dummy prefetch on last group
    int2 en[4];
    float4 rn[4];
#pragma unroll
    for (int j = 0; j < 4; ++j) en[j] = kpw[wv][kn + j];
#pragma unroll
    for (int j = 0; j < 4; ++j) rn[j] = *(const float4*)(pb + (size_t)en[j].x * C_DIM);
#pragma unroll
    for (int j = 0; j < 4; ++j) {
      float w = __int_as_float(e[j].y);
      a0 = fmaf(w, r[j].x, a0); a1 = fmaf(w, r[j].y, a1);
      a2 = fmaf(w, r[j].z, a2); a3 = fmaf(w, r[j].w, a3);
    }
#pragma unroll
    for (int j = 0; j < 4; ++j) { e[j] = en[j]; r[j] = rn[j]; }
  }
  a0 *= invS; a1 *= invS; a2 *= invS; a3 *= invS;

  *(float4*)&tbuf[wv][4 * lane] = make_float4(a0, a1, a2, a3);
  __syncthreads();

  // coalesced store: thread t -> c = t>>1, pixel quad = (t&1)*4
  {
    int c = t >> 1, lq = t & 1;
    float4 o = make_float4(tbuf[4 * lq + 0][c], tbuf[4 * lq + 1][c],
                           tbuf[4 * lq + 2][c], tbuf[4 * lq + 3][c]);
    *(float4*)(out + ((size_t)(n * C_DIM + c)) * L_DIM + l0 + 4 * lq) = o;
  }
}

// ---------------- launch ----------------
extern "C" void kernel_launch(void* const* d_in, const int* in_sizes, int n_in,
                              void* d_out, int out_size, void* d_ws, size_t ws_size,
                              hipStream_t stream) {
  const float* x = (const float*)d_in[0];
  const float* pool = (const float*)d_in[1];
  float* out = (float*)d_out;
  float* poolTs = (float*)d_ws;                          // 2 MB
  float* pinv = poolTs + (size_t)C_DIM * P_DIM;          // + 8 KB
  float* sbuf = pinv + P_DIM;                            // 134.2 MB scores
  k_pinv<<<P_DIM / 256, 256, 0, stream>>>(pool, pinv);
  k_transpose<<<(P_DIM / 32) * (C_DIM / 32), 256, 0, stream>>>(pool, pinv, poolTs);
  k_gemm<<<16 * 128, 256, 0, stream>>>(poolTs, x, sbuf);
  k_select<<<2048, 512, 0, stream>>>(sbuf, pool, out);
}

// Round 8
// 328.222 us; speedup vs baseline: 2.4141x; 1.1475x over previous
//
#include <hip/hip_runtime.h>

typedef unsigned short u16;
typedef short short8 __attribute__((ext_vector_type(8)));
typedef float floatx4 __attribute__((ext_vector_type(4)));

#define C_DIM 256
#define P_DIM 2048
#define L_DIM 1024
#define N_DIM 16
#define KEEP 102
#define KPAD 108
#define HALF_PIX 8192   // pixels per half-pass

__device__ __forceinline__ u16 f2bf(float f) {   // RNE fp32 -> bf16 bits
  unsigned u = __float_as_uint(f);
  u += 0x7fffu + ((u >> 16) & 1u);
  return (u16)(u >> 16);
}
__device__ __forceinline__ float bf2f(u16 h) {
  return __uint_as_float(((unsigned)h) << 16);
}
__device__ __forceinline__ void st8(u16* dst, const u16* s) {
  uint4 u;
  u.x = (unsigned)s[0] | ((unsigned)s[1] << 16);
  u.y = (unsigned)s[2] | ((unsigned)s[3] << 16);
  u.z = (unsigned)s[4] | ((unsigned)s[5] << 16);
  u.w = (unsigned)s[6] | ((unsigned)s[7] << 16);
  *(uint4*)dst = u;
}

// ---------------- kernel 1a: pinv[p] = 1/||pool_p|| ----------------
__global__ __launch_bounds__(256) void k_pinv(const float* __restrict__ pool,
                                              float* __restrict__ pinv) {
  int p = blockIdx.x * 256 + threadIdx.x;
  const float4* row = (const float4*)(pool + (size_t)p * C_DIM);
  float s = 0.f;
#pragma unroll
  for (int i = 0; i < C_DIM / 4; ++i) {
    float4 v = row[i];
    s += v.x * v.x + v.y * v.y + v.z * v.z + v.w * v.w;
  }
  pinv[p] = 1.0f / sqrtf(s);
}

// ------- kernel 1b: pack pool*pinv into MFMA-A fragment order, 3-way split ----
// frag element (pm, ks, lane, j): p = pm*16 + (lane&15), c = ks*32 + (lane>>4)*8 + j
__global__ __launch_bounds__(256) void k_packpool(const float* __restrict__ pool,
                                                  const float* __restrict__ pinv,
                                                  u16* __restrict__ ah,
                                                  u16* __restrict__ am,
                                                  u16* __restrict__ al) {
  int tid = blockIdx.x * 256 + threadIdx.x;     // 65536 = 128*8*64
  int lane = tid & 63;
  int ks = (tid >> 6) & 7;
  int pm = tid >> 9;
  int p = pm * 16 + (lane & 15);
  int c0 = ks * 32 + ((lane >> 4) << 3);
  float sc = pinv[p];
  const float* src = pool + (size_t)p * C_DIM + c0;
  u16 h8[8], m8[8], l8[8];
#pragma unroll
  for (int j = 0; j < 8; ++j) {
    float v = src[j] * sc;
    u16 h = f2bf(v); float fh = bf2f(h);
    float r1 = v - fh; u16 m = f2bf(r1); float fm = bf2f(m);
    float r2 = r1 - fm; u16 l = f2bf(r2);
    h8[j] = h; m8[j] = m; l8[j] = l;
  }
  size_t o = (size_t)tid * 8;
  st8(ah + o, h8); st8(am + o, m8); st8(al + o, l8);
}

// ------- kernel 1c: pack x into MFMA-B fragment order, 3-way split ----------
// frag element (pn, ks, lane, j): pix = pn*16 + (lane&15), c = ks*32 + (lane>>4)*8 + j
__global__ __launch_bounds__(256) void k_packx(const float* __restrict__ x,
                                               u16* __restrict__ xh,
                                               u16* __restrict__ xm,
                                               u16* __restrict__ xl) {
  int tid = blockIdx.x * 256 + threadIdx.x;     // 524288 = 1024*8*64
  int lane = tid & 63;
  int ks = (tid >> 6) & 7;
  int pn = tid >> 9;
  int pix = pn * 16 + (lane & 15);
  int n = pix >> 10, l = pix & 1023;
  int c0 = ks * 32 + ((lane >> 4) << 3);
  const float* src = x + ((size_t)(n * C_DIM + c0)) * L_DIM + l;
  u16 h8[8], m8[8], l8[8];
#pragma unroll
  for (int j = 0; j < 8; ++j) {
    float v = src[(size_t)j * L_DIM];
    u16 h = f2bf(v); float fh = bf2f(h);
    float r1 = v - fh; u16 m = f2bf(r1); float fm = bf2f(m);
    float r2 = r1 - fm; u16 l2 = f2bf(r2);
    h8[j] = h; m8[j] = m; l8[j] = l2;
  }
  size_t o = (size_t)tid * 8;
  st8(xh + o, h8); st8(xm + o, m8); st8(xl + o, l8);
}

// ---------------- kernel A: sbuf[pixLocal][p] via bf16x3 MFMA (6 products) ---
// One half (8192 pixels). grid 1024 = pT(16) x pixT(64); 256 thr / 4 waves.
// Wave w: p in [pT*128 + w*32, +32), pixels [pixT*128, +128). No LDS.
__global__ __launch_bounds__(256, 3) void k_mfma(const u16* __restrict__ ah_,
                                                 const u16* __restrict__ am_,
                                                 const u16* __restrict__ al_,
                                                 const u16* __restrict__ xh_,
                                                 const u16* __restrict__ xm_,
                                                 const u16* __restrict__ xl_,
                                                 float* __restrict__ sbuf,
                                                 int half) {
  const int t = threadIdx.x, lane = t & 63, w = t >> 6;
  const int pT = blockIdx.x & 15, pixT = blockIdx.x >> 4;   // pixT 0..63
  const int pmBase = pT * 8 + w * 2;            // two 16-row A tiles per wave
  const int pnBase = half * 512 + pixT * 8;     // eight 16-col B tiles (global)
  const short8* A8h = (const short8*)ah_;
  const short8* A8m = (const short8*)am_;
  const short8* A8l = (const short8*)al_;
  const short8* B8h = (const short8*)xh_;
  const short8* B8m = (const short8*)xm_;
  const short8* B8l = (const short8*)xl_;

  floatx4 acc[2][8];
#pragma unroll
  for (int mt = 0; mt < 2; ++mt)
#pragma unroll
    for (int nt = 0; nt < 8; ++nt) acc[mt][nt] = (floatx4){0.f, 0.f, 0.f, 0.f};

#pragma unroll 1
  for (int ks = 0; ks < 8; ++ks) {
    const size_t ao = (size_t)ks * 64 + lane;
    short8 aH[2], aM[2], aL[2];
#pragma unroll
    for (int mt = 0; mt < 2; ++mt) {
      size_t idx = (size_t)(pmBase + mt) * 512 + ao;
      aH[mt] = A8h[idx]; aM[mt] = A8m[idx]; aL[mt] = A8l[idx];
    }
#pragma unroll
    for (int nt = 0; nt < 8; ++nt) {
      size_t bidx = (size_t)(pnBase + nt) * 512 + ao;
      short8 bh = B8h[bidx], bm = B8m[bidx], bl = B8l[bidx];
#pragma unroll
      for (int mt = 0; mt < 2; ++mt) {
        floatx4 c = acc[mt][nt];
        c = __builtin_amdgcn_mfma_f32_16x16x32_bf16(aH[mt], bh, c, 0, 0, 0);
        c = __builtin_amdgcn_mfma_f32_16x16x32_bf16(aH[mt], bm, c, 0, 0, 0);
        c = __builtin_amdgcn_mfma_f32_16x16x32_bf16(aM[mt], bh, c, 0, 0, 0);
        c = __builtin_amdgcn_mfma_f32_16x16x32_bf16(aH[mt], bl, c, 0, 0, 0);
        c = __builtin_amdgcn_mfma_f32_16x16x32_bf16(aM[mt], bm, c, 0, 0, 0);
        c = __builtin_amdgcn_mfma_f32_16x16x32_bf16(aL[mt], bh, c, 0, 0, 0);
        acc[mt][nt] = c;
      }
    }
  }

  // epilogue: D layout col(pix)=lane&15, row(p)=quad*4+reg -> reg quad is 4
  // consecutive p -> one float4 store per (mt,nt). No LDS.
  const int qr = lane >> 4, cl = lane & 15;
  const int pix0 = pixT * 128;                  // local to this half
  const int pbase = pT * 128 + w * 32;
#pragma unroll
  for (int mt = 0; mt < 2; ++mt)
#pragma unroll
    for (int nt = 0; nt < 8; ++nt) {
      float* dst = sbuf + (size_t)(pix0 + nt * 16 + cl) * P_DIM + pbase + mt * 16 + qr * 4;
      *(float4*)dst = make_float4(acc[mt][nt][0], acc[mt][nt][1],
                                  acc[mt][nt][2], acc[mt][nt][3]);
    }
}

// ---------------- kernel B: per-pixel top-102 select + renorm + recon ----
// One half. 512 threads = 8 waves; wave wv owns one pixel. 1024 blocks.
// value (q, rr) at lane: p = q*256 + lane*4 + rr
__global__ __launch_bounds__(512) void k_select(const float* __restrict__ sbuf,
                                                const float* __restrict__ pool,
                                                float* __restrict__ out,
                                                int half) {
  __shared__ __align__(16) float tbuf[8][260];
  __shared__ int2 kpw[8][KPAD];

  const int t = threadIdx.x;
  const int lane = t & 63;
  const int wv = t >> 6;
  const int b = blockIdx.x;
  const int gp0 = half * HALF_PIX + b * 8;      // global pixel base (8-aligned)
  const int n = gp0 >> 10;
  const int l0 = gp0 & 1023;
  const float* sp = sbuf + (size_t)(b * 8 + wv) * P_DIM;

  float4 v[8];
#pragma unroll
  for (int q = 0; q < 8; ++q) v[q] = *(const float4*)(sp + q * 256 + lane * 4);

  if (lane < KPAD - KEEP) kpw[wv][KEEP + lane] = make_int2(0, 0);

  unsigned lo = 0u, hi = 0x7F800000u;
  for (int it = 0; it < 31; ++it) {
    unsigned m = lo + ((hi - lo) >> 1);
    float mf = __uint_as_float(m);
    unsigned cnt = 0;
#pragma unroll
    for (int q = 0; q < 8; ++q) {
      cnt += (unsigned)__popcll(__ballot(fabsf(v[q].x) >= mf));
      cnt += (unsigned)__popcll(__ballot(fabsf(v[q].y) >= mf));
      cnt += (unsigned)__popcll(__ballot(fabsf(v[q].z) >= mf));
      cnt += (unsigned)__popcll(__ballot(fabsf(v[q].w) >= mf));
    }
    if (cnt >= KEEP) lo = m; else hi = m;
  }
  const float V = __uint_as_float(lo);
  const float Vp = __uint_as_float(lo + 1u);

  unsigned gt = 0;
#pragma unroll
  for (int q = 0; q < 8; ++q) {
    gt += (unsigned)__popcll(__ballot(fabsf(v[q].x) >= Vp));
    gt += (unsigned)__popcll(__ballot(fabsf(v[q].y) >= Vp));
    gt += (unsigned)__popcll(__ballot(fabsf(v[q].z) >= Vp));
    gt += (unsigned)__popcll(__ballot(fabsf(v[q].w) >= Vp));
  }
  const unsigned rrem = (unsigned)KEEP - gt;

  unsigned gmask[8], tmask[8];
#pragma unroll
  for (int q = 0; q < 8; ++q) {
    const float* f = (const float*)&v[q];
    unsigned gm = 0, tm = 0;
#pragma unroll
    for (int rr = 0; rr < 4; ++rr) {
      float av = fabsf(f[rr]);
      if (av >= Vp) gm |= (1u << rr);
      else if (av >= V) tm |= (1u << rr);
    }
    gmask[q] = gm; tmask[q] = tm;
  }

  const unsigned long long lowm = (1ull << lane) - 1ull;
  unsigned base = 0, tiebase = 0;
  float Ssum = 0.f;
#pragma unroll
  for (int q = 0; q < 8; ++q) {
    const float* f = (const float*)&v[q];
    unsigned teq = 0, myeqb = 0;
#pragma unroll
    for (int rr = 0; rr < 4; ++rr) {
      unsigned long long beq = __ballot((tmask[q] >> rr) & 1u);
      teq += (unsigned)__popcll(beq);
      myeqb += (unsigned)__popcll(beq & lowm);
    }
    unsigned km = gmask[q];
    {
      unsigned cum = 0;
#pragma unroll
      for (int rr = 0; rr < 4; ++rr) {
        if ((tmask[q] >> rr) & 1u) {
          if (tiebase + myeqb + cum < rrem) km |= (1u << rr);
          ++cum;
        }
      }
    }
    unsigned long long bk[4];
    unsigned tot = 0, myb = 0;
#pragma unroll
    for (int rr = 0; rr < 4; ++rr) {
      bk[rr] = __ballot((km >> rr) & 1u);
      tot += (unsigned)__popcll(bk[rr]);
      myb += (unsigned)__popcll(bk[rr] & lowm);
    }
    {
      unsigned cum = 0;
#pragma unroll
      for (int rr = 0; rr < 4; ++rr) {
        if ((km >> rr) & 1u) {
          unsigned pos = base + myb + cum;
          kpw[wv][pos] = make_int2(q * 256 + lane * 4 + rr, __float_as_int(f[rr]));
          Ssum += f[rr];
          ++cum;
        }
      }
    }
    base += tot;
    tiebase += teq;
  }

#pragma unroll
  for (int off = 1; off < 64; off <<= 1) Ssum += __shfl_xor(Ssum, off);
  const float invS = 1.0f / Ssum;

  __builtin_amdgcn_wave_barrier();

  float a0 = 0.f, a1 = 0.f, a2 = 0.f, a3 = 0.f;
  const float* pb = pool + 4 * lane;
  int2 e[4];
  float4 r[4];
#pragma unroll
  for (int j = 0; j < 4; ++j) e[j] = kpw[wv][j];
#pragma unroll
  for (int j = 0; j < 4; ++j) r[j] = *(const float4*)(pb + (size_t)e[j].x * C_DIM);
  for (int k = 0; k < 104; k += 4) {
    int kn = (k + 4 < 104) ? k + 4 : 0;
    int2 en[4];
    float4 rn[4];
#pragma unroll
    for (int j = 0; j < 4; ++j) en[j] = kpw[wv][kn + j];
#pragma unroll
    for (int j = 0; j < 4; ++j) rn[j] = *(const float4*)(pb + (size_t)en[j].x * C_DIM);
#pragma unroll
    for (int j = 0; j < 4; ++j) {
      float w = __int_as_float(e[j].y);
      a0 = fmaf(w, r[j].x, a0); a1 = fmaf(w, r[j].y, a1);
      a2 = fmaf(w, r[j].z, a2); a3 = fmaf(w, r[j].w, a3);
    }
#pragma unroll
    for (int j = 0; j < 4; ++j) { e[j] = en[j]; r[j] = rn[j]; }
  }
  a0 *= invS; a1 *= invS; a2 *= invS; a3 *= invS;

  *(float4*)&tbuf[wv][4 * lane] = make_float4(a0, a1, a2, a3);
  __syncthreads();

  {
    int c = t >> 1, lq = t & 1;
    float4 o = make_float4(tbuf[4 * lq + 0][c], tbuf[4 * lq + 1][c],
                           tbuf[4 * lq + 2][c], tbuf[4 * lq + 3][c]);
    *(float4*)(out + ((size_t)(n * C_DIM + c)) * L_DIM + l0 + 4 * lq) = o;
  }
}

// ---------------- launch ----------------
// d_ws layout (94.1 MB total, all within the proven-safe 136 MB):
//   sbuf      67,108,864 B   (8192 x 2048 fp32, reused across the two halves)
//   xh/xm/xl   8,388,608 B each
//   ah/am/al   1,048,576 B each
//   pinv           8,192 B
extern "C" void kernel_launch(void* const* d_in, const int* in_sizes, int n_in,
                              void* d_out, int out_size, void* d_ws, size_t ws_size,
                              hipStream_t stream) {
  const float* x = (const float*)d_in[0];
  const float* pool = (const float*)d_in[1];
  float* out = (float*)d_out;
  char* wsb = (char*)d_ws;
  float* sbuf = (float*)wsb;
  u16* xh = (u16*)(wsb + 67108864);
  u16* xm = xh + 4194304;
  u16* xl = xm + 4194304;
  u16* ah = xl + 4194304;
  u16* am = ah + 524288;
  u16* al = am + 524288;
  float* pinv = (float*)(al + 524288);

  k_pinv<<<P_DIM / 256, 256, 0, stream>>>(pool, pinv);
  k_packpool<<<256, 256, 0, stream>>>(pool, pinv, ah, am, al);
  k_packx<<<2048, 256, 0, stream>>>(x, xh, xm, xl);
  for (int h = 0; h < 2; ++h) {
    k_mfma<<<1024, 256, 0, stream>>>(ah, am, al, xh, xm, xl, sbuf, h);
    k_select<<<1024, 512, 0, stream>>>(sbuf, pool, out, h);
  }
}

// Round 9
// 318.743 us; speedup vs baseline: 2.4859x; 1.0297x over previous
//
#include <hip/hip_runtime.h>
#include <hip/hip_fp16.h>

typedef unsigned short u16;
typedef short short8 __attribute__((ext_vector_type(8)));
typedef float floatx4 __attribute__((ext_vector_type(4)));

#define C_DIM 256
#define P_DIM 2048
#define L_DIM 1024
#define N_DIM 16
#define KEEP 102
#define KPAD 112
#define HALF_PIX 8192   // pixels per half-pass

__device__ __forceinline__ u16 f2bf(float f) {   // RNE fp32 -> bf16 bits
  unsigned u = __float_as_uint(f);
  u += 0x7fffu + ((u >> 16) & 1u);
  return (u16)(u >> 16);
}
__device__ __forceinline__ float bf2f(u16 h) {
  return __uint_as_float(((unsigned)h) << 16);
}
__device__ __forceinline__ void st8(u16* dst, const u16* s) {
  uint4 u;
  u.x = (unsigned)s[0] | ((unsigned)s[1] << 16);
  u.y = (unsigned)s[2] | ((unsigned)s[3] << 16);
  u.z = (unsigned)s[4] | ((unsigned)s[5] << 16);
  u.w = (unsigned)s[6] | ((unsigned)s[7] << 16);
  *(uint4*)dst = u;
}

// ---------------- kernel 1a: pinv[p] = 1/||pool_p|| ----------------
__global__ __launch_bounds__(256) void k_pinv(const float* __restrict__ pool,
                                              float* __restrict__ pinv) {
  int p = blockIdx.x * 256 + threadIdx.x;
  const float4* row = (const float4*)(pool + (size_t)p * C_DIM);
  float s = 0.f;
#pragma unroll
  for (int i = 0; i < C_DIM / 4; ++i) {
    float4 v = row[i];
    s += v.x * v.x + v.y * v.y + v.z * v.z + v.w * v.w;
  }
  pinv[p] = 1.0f / sqrtf(s);
}

// ------- kernel 1b: pack pool*pinv into MFMA-A frag order (3-way split),
//         and a raw fp16 copy of pool for the recon gather -------------------
// frag element (pm, ks, lane, j): p = pm*16 + (lane&15), c = ks*32 + (lane>>4)*8 + j
__global__ __launch_bounds__(256) void k_packpool(const float* __restrict__ pool,
                                                  const float* __restrict__ pinv,
                                                  u16* __restrict__ ah,
                                                  u16* __restrict__ am,
                                                  u16* __restrict__ al,
                                                  u16* __restrict__ ph) {
  int tid = blockIdx.x * 256 + threadIdx.x;     // 65536 = 128*8*64
  int lane = tid & 63;
  int ks = (tid >> 6) & 7;
  int pm = tid >> 9;
  int p = pm * 16 + (lane & 15);
  int c0 = ks * 32 + ((lane >> 4) << 3);
  float sc = pinv[p];
  const float* src = pool + (size_t)p * C_DIM + c0;
  u16 h8[8], m8[8], l8[8], p8[8];
#pragma unroll
  for (int j = 0; j < 8; ++j) {
    float raw = src[j];
    p8[j] = __half_as_ushort(__float2half(raw));
    float v = raw * sc;
    u16 h = f2bf(v); float fh = bf2f(h);
    float r1 = v - fh; u16 m = f2bf(r1); float fm = bf2f(m);
    float r2 = r1 - fm; u16 l = f2bf(r2);
    h8[j] = h; m8[j] = m; l8[j] = l;
  }
  size_t o = (size_t)tid * 8;
  st8(ah + o, h8); st8(am + o, m8); st8(al + o, l8);
  st8(ph + (size_t)p * C_DIM + c0, p8);
}

// ------- kernel 1c: pack x into MFMA-B fragment order, 3-way split ----------
// frag element (pn, ks, lane, j): pix = pn*16 + (lane&15), c = ks*32 + (lane>>4)*8 + j
__global__ __launch_bounds__(256) void k_packx(const float* __restrict__ x,
                                               u16* __restrict__ xh,
                                               u16* __restrict__ xm,
                                               u16* __restrict__ xl) {
  int tid = blockIdx.x * 256 + threadIdx.x;     // 524288 = 1024*8*64
  int lane = tid & 63;
  int ks = (tid >> 6) & 7;
  int pn = tid >> 9;
  int pix = pn * 16 + (lane & 15);
  int n = pix >> 10, l = pix & 1023;
  int c0 = ks * 32 + ((lane >> 4) << 3);
  const float* src = x + ((size_t)(n * C_DIM + c0)) * L_DIM + l;
  u16 h8[8], m8[8], l8[8];
#pragma unroll
  for (int j = 0; j < 8; ++j) {
    float v = src[(size_t)j * L_DIM];
    u16 h = f2bf(v); float fh = bf2f(h);
    float r1 = v - fh; u16 m = f2bf(r1); float fm = bf2f(m);
    float r2 = r1 - fm; u16 l2 = f2bf(r2);
    h8[j] = h; m8[j] = m; l8[j] = l2;
  }
  size_t o = (size_t)tid * 8;
  st8(xh + o, h8); st8(xm + o, m8); st8(xl + o, l8);
}

// ---------------- kernel A: sbuf[pixLocal][p] via bf16x3 MFMA (6 products) ---
// One half (8192 pixels). grid 1024 = pT(16) x pixT(64); 256 thr / 4 waves.
__global__ __launch_bounds__(256, 3) void k_mfma(const u16* __restrict__ ah_,
                                                 const u16* __restrict__ am_,
                                                 const u16* __restrict__ al_,
                                                 const u16* __restrict__ xh_,
                                                 const u16* __restrict__ xm_,
                                                 const u16* __restrict__ xl_,
                                                 float* __restrict__ sbuf,
                                                 int half) {
  const int t = threadIdx.x, lane = t & 63, w = t >> 6;
  const int pT = blockIdx.x & 15, pixT = blockIdx.x >> 4;   // pixT 0..63
  const int pmBase = pT * 8 + w * 2;
  const int pnBase = half * 512 + pixT * 8;
  const short8* A8h = (const short8*)ah_;
  const short8* A8m = (const short8*)am_;
  const short8* A8l = (const short8*)al_;
  const short8* B8h = (const short8*)xh_;
  const short8* B8m = (const short8*)xm_;
  const short8* B8l = (const short8*)xl_;

  floatx4 acc[2][8];
#pragma unroll
  for (int mt = 0; mt < 2; ++mt)
#pragma unroll
    for (int nt = 0; nt < 8; ++nt) acc[mt][nt] = (floatx4){0.f, 0.f, 0.f, 0.f};

#pragma unroll 1
  for (int ks = 0; ks < 8; ++ks) {
    const size_t ao = (size_t)ks * 64 + lane;
    short8 aH[2], aM[2], aL[2];
#pragma unroll
    for (int mt = 0; mt < 2; ++mt) {
      size_t idx = (size_t)(pmBase + mt) * 512 + ao;
      aH[mt] = A8h[idx]; aM[mt] = A8m[idx]; aL[mt] = A8l[idx];
    }
#pragma unroll
    for (int nt = 0; nt < 8; ++nt) {
      size_t bidx = (size_t)(pnBase + nt) * 512 + ao;
      short8 bh = B8h[bidx], bm = B8m[bidx], bl = B8l[bidx];
#pragma unroll
      for (int mt = 0; mt < 2; ++mt) {
        floatx4 c = acc[mt][nt];
        c = __builtin_amdgcn_mfma_f32_16x16x32_bf16(aH[mt], bh, c, 0, 0, 0);
        c = __builtin_amdgcn_mfma_f32_16x16x32_bf16(aH[mt], bm, c, 0, 0, 0);
        c = __builtin_amdgcn_mfma_f32_16x16x32_bf16(aM[mt], bh, c, 0, 0, 0);
        c = __builtin_amdgcn_mfma_f32_16x16x32_bf16(aH[mt], bl, c, 0, 0, 0);
        c = __builtin_amdgcn_mfma_f32_16x16x32_bf16(aM[mt], bm, c, 0, 0, 0);
        c = __builtin_amdgcn_mfma_f32_16x16x32_bf16(aL[mt], bh, c, 0, 0, 0);
        acc[mt][nt] = c;
      }
    }
  }

  const int qr = lane >> 4, cl = lane & 15;
  const int pix0 = pixT * 128;
  const int pbase = pT * 128 + w * 32;
#pragma unroll
  for (int mt = 0; mt < 2; ++mt)
#pragma unroll
    for (int nt = 0; nt < 8; ++nt) {
      float* dst = sbuf + (size_t)(pix0 + nt * 16 + cl) * P_DIM + pbase + mt * 16 + qr * 4;
      *(float4*)dst = make_float4(acc[mt][nt][0], acc[mt][nt][1],
                                  acc[mt][nt][2], acc[mt][nt][3]);
    }
}

// ---------------- kernel B: per-pixel top-102 select + renorm + recon ----
// One half. 512 threads = 8 waves; wave wv owns one pixel. 1024 blocks.
// value (q, rr) at lane: p = q*256 + lane*4 + rr
__global__ __launch_bounds__(512) void k_select(const float* __restrict__ sbuf,
                                                const u16* __restrict__ pool_h,
                                                float* __restrict__ out,
                                                int half) {
  __shared__ __align__(16) float tbuf[8][260];
  __shared__ int2 kpw[8][KPAD];

  const int t = threadIdx.x;
  const int lane = t & 63;
  const int wv = t >> 6;
  const int b = blockIdx.x;
  const int gp0 = half * HALF_PIX + b * 8;
  const int n = gp0 >> 10;
  const int l0 = gp0 & 1023;
  const float* sp = sbuf + (size_t)(b * 8 + wv) * P_DIM;

  float4 v[8];
#pragma unroll
  for (int q = 0; q < 8; ++q) v[q] = *(const float4*)(sp + q * 256 + lane * 4);

  if (lane < KPAD - KEEP) kpw[wv][KEEP + lane] = make_int2(0, 0);

  // ---- wave max of |s| -> tight search bounds ----
  float M = 0.f;
#pragma unroll
  for (int q = 0; q < 8; ++q) {
    M = fmaxf(M, fabsf(v[q].x)); M = fmaxf(M, fabsf(v[q].y));
    M = fmaxf(M, fabsf(v[q].z)); M = fmaxf(M, fabsf(v[q].w));
  }
#pragma unroll
  for (int off = 1; off < 64; off <<= 1) M = fmaxf(M, __shfl_xor(M, off));
  const unsigned bitsM = __float_as_uint(M);

  // ---- exact binary search on positive-float bit pattern, early exit.
  //      invariant: count(>=lo) >= KEEP > count(>=hi) ----
  unsigned lo = 0u, hi = bitsM + 1u;
  unsigned m = (bitsM > (5u << 23)) ? (bitsM - (5u << 23)) : ((lo + hi) >> 1);
  while (hi - lo > 1u) {
    float mf = __uint_as_float(m);
    unsigned cnt = 0;
#pragma unroll
    for (int q = 0; q < 8; ++q) {
      cnt += (unsigned)__popcll(__ballot(fabsf(v[q].x) >= mf));
      cnt += (unsigned)__popcll(__ballot(fabsf(v[q].y) >= mf));
      cnt += (unsigned)__popcll(__ballot(fabsf(v[q].z) >= mf));
      cnt += (unsigned)__popcll(__ballot(fabsf(v[q].w) >= mf));
    }
    if (cnt >= KEEP) lo = m; else hi = m;
    m = lo + ((hi - lo) >> 1);
  }
  const float V = __uint_as_float(lo);
  const float Vp = __uint_as_float(lo + 1u);

  unsigned gt = 0;
#pragma unroll
  for (int q = 0; q < 8; ++q) {
    gt += (unsigned)__popcll(__ballot(fabsf(v[q].x) >= Vp));
    gt += (unsigned)__popcll(__ballot(fabsf(v[q].y) >= Vp));
    gt += (unsigned)__popcll(__ballot(fabsf(v[q].z) >= Vp));
    gt += (unsigned)__popcll(__ballot(fabsf(v[q].w) >= Vp));
  }
  const unsigned rrem = (unsigned)KEEP - gt;

  unsigned gmask[8], tmask[8];
#pragma unroll
  for (int q = 0; q < 8; ++q) {
    const float* f = (const float*)&v[q];
    unsigned gm = 0, tm = 0;
#pragma unroll
    for (int rr = 0; rr < 4; ++rr) {
      float av = fabsf(f[rr]);
      if (av >= Vp) gm |= (1u << rr);
      else if (av >= V) tm |= (1u << rr);
    }
    gmask[q] = gm; tmask[q] = tm;
  }

  const unsigned long long lowm = (1ull << lane) - 1ull;
  unsigned base = 0, tiebase = 0;
  float Ssum = 0.f;
#pragma unroll
  for (int q = 0; q < 8; ++q) {
    const float* f = (const float*)&v[q];
    unsigned teq = 0, myeqb = 0;
#pragma unroll
    for (int rr = 0; rr < 4; ++rr) {
      unsigned long long beq = __ballot((tmask[q] >> rr) & 1u);
      teq += (unsigned)__popcll(beq);
      myeqb += (unsigned)__popcll(beq & lowm);
    }
    unsigned km = gmask[q];
    {
      unsigned cum = 0;
#pragma unroll
      for (int rr = 0; rr < 4; ++rr) {
        if ((tmask[q] >> rr) & 1u) {
          if (tiebase + myeqb + cum < rrem) km |= (1u << rr);
          ++cum;
        }
      }
    }
    unsigned long long bk[4];
    unsigned tot = 0, myb = 0;
#pragma unroll
    for (int rr = 0; rr < 4; ++rr) {
      bk[rr] = __ballot((km >> rr) & 1u);
      tot += (unsigned)__popcll(bk[rr]);
      myb += (unsigned)__popcll(bk[rr] & lowm);
    }
    {
      unsigned cum = 0;
#pragma unroll
      for (int rr = 0; rr < 4; ++rr) {
        if ((km >> rr) & 1u) {
          unsigned pos = base + myb + cum;
          kpw[wv][pos] = make_int2(q * 256 + lane * 4 + rr, __float_as_int(f[rr]));
          Ssum += f[rr];
          ++cum;
        }
      }
    }
    base += tot;
    tiebase += teq;
  }

#pragma unroll
  for (int off = 1; off < 64; off <<= 1) Ssum += __shfl_xor(Ssum, off);
  const float invS = 1.0f / Ssum;

  __builtin_amdgcn_wave_barrier();

  // ---- recon: out_c = invS * sum_kept s_p * pool_h[p][c], c = 4*lane+j
  //      fp16 rows (512 B/wave), 4-wide groups, 1-group-ahead prefetch ----
  float a0 = 0.f, a1 = 0.f, a2 = 0.f, a3 = 0.f;
  const u16* pb = pool_h + 4 * lane;
  int2 e[4];
  uint2 r[4];
#pragma unroll
  for (int j = 0; j < 4; ++j) e[j] = kpw[wv][j];
#pragma unroll
  for (int j = 0; j < 4; ++j) r[j] = *(const uint2*)(pb + (size_t)e[j].x * C_DIM);
  for (int k = 0; k < KPAD; k += 4) {
    int kn = (k + 4 < KPAD) ? k + 4 : 0;
    int2 en[4];
    uint2 rn[4];
#pragma unroll
    for (int j = 0; j < 4; ++j) en[j] = kpw[wv][kn + j];
#pragma unroll
    for (int j = 0; j < 4; ++j) rn[j] = *(const uint2*)(pb + (size_t)en[j].x * C_DIM);
#pragma unroll
    for (int j = 0; j < 4; ++j) {
      float w = __int_as_float(e[j].y);
      float f0 = __half2float(__ushort_as_half((u16)(r[j].x & 0xffffu)));
      float f1 = __half2float(__ushort_as_half((u16)(r[j].x >> 16)));
      float f2 = __half2float(__ushort_as_half((u16)(r[j].y & 0xffffu)));
      float f3 = __half2float(__ushort_as_half((u16)(r[j].y >> 16)));
      a0 = fmaf(w, f0, a0); a1 = fmaf(w, f1, a1);
      a2 = fmaf(w, f2, a2); a3 = fmaf(w, f3, a3);
    }
#pragma unroll
    for (int j = 0; j < 4; ++j) { e[j] = en[j]; r[j] = rn[j]; }
  }
  a0 *= invS; a1 *= invS; a2 *= invS; a3 *= invS;

  *(float4*)&tbuf[wv][4 * lane] = make_float4(a0, a1, a2, a3);
  __syncthreads();

  {
    int c = t >> 1, lq = t & 1;
    float4 o = make_float4(tbuf[4 * lq + 0][c], tbuf[4 * lq + 1][c],
                           tbuf[4 * lq + 2][c], tbuf[4 * lq + 3][c]);
    *(float4*)(out + ((size_t)(n * C_DIM + c)) * L_DIM + l0 + 4 * lq) = o;
  }
}

// ---------------- launch ----------------
// d_ws layout (96.5 MB, within the proven-safe budget):
//   sbuf 67,108,864 | xh/xm/xl 3 x 8,388,608 | ah/am/al 3 x 1,048,576
//   pool_h 1,048,576 | pinv 8,192
extern "C" void kernel_launch(void* const* d_in, const int* in_sizes, int n_in,
                              void* d_out, int out_size, void* d_ws, size_t ws_size,
                              hipStream_t stream) {
  const float* x = (const float*)d_in[0];
  const float* pool = (const float*)d_in[1];
  float* out = (float*)d_out;
  char* wsb = (char*)d_ws;
  float* sbuf = (float*)wsb;
  u16* xh = (u16*)(wsb + 67108864);
  u16* xm = xh + 4194304;
  u16* xl = xm + 4194304;
  u16* ah = xl + 4194304;
  u16* am = ah + 524288;
  u16* al = am + 524288;
  u16* ph = al + 524288;
  float* pinv = (float*)(ph + 524288);

  k_pinv<<<P_DIM / 256, 256, 0, stream>>>(pool, pinv);
  k_packpool<<<256, 256, 0, stream>>>(pool, pinv, ah, am, al, ph);
  k_packx<<<2048, 256, 0, stream>>>(x, xh, xm, xl);
  for (int h = 0; h < 2; ++h) {
    k_mfma<<<1024, 256, 0, stream>>>(ah, am, al, xh, xm, xl, sbuf, h);
    k_select<<<1024, 512, 0, stream>>>(sbuf, ph, out, h);
  }
}